// Round 10
// baseline (194.305 us; speedup 1.0000x reference)
//
#include <hip/hip_runtime.h>
#include <hip/hip_bf16.h>
#include <stdint.h>

// StrideGraphSAGE on MI355X (gfx950).
// h_l = elu(agg @ Wl[l] + bl[l] + nodes @ Wr[l]); out = concat(h_0..h_3, x) along C.
// agg is nonzero only for rows < 1089; edge set = deterministic stride-2 grid.
//
// R10: persistent multi-job GEMM. R4's verified 128^2 / 3-ring / counted-vmcnt
// core, but each block owns slot s and processes brows {s+96g} (5-6 tiles) at
// fixed bcol, pipeline continuous across tile boundaries. Grid 768 = 3/CU exact.
// Epilogue stores share vmcnt -> post-epilogue step waits vmcnt(0) (in-order).

#define C_DIM 256
#define GRID_G 33
#define N_NODES 1089
#define BATCH 64
#define TOTAL (BATCH * N_NODES)     // 69696
#define M_PAD 69760
#define CN (C_DIM * N_NODES)        // 278784
#define OUT_STRIDE_B (5 * CN)       // 1393920
#define NCOLS 1024
#define AGG_ROWS 1152               // 9 tiles of 128; rows 1089..1151 zeroed

using bf16 = __hip_bfloat16;
typedef __attribute__((ext_vector_type(8))) short short8;
typedef __attribute__((ext_vector_type(4))) float f32x4;

// ---- workspace layout (bytes) ----
#define NODES_BYTES ((size_t)M_PAD * C_DIM * 2)
#define OFF_NODES   ((size_t)0)
#define OFF_AGGB    (NODES_BYTES)
#define AGGB_BYTES  ((size_t)AGG_ROWS * C_DIM * 2)
#define OFF_WLT     (OFF_AGGB + AGGB_BYTES)
#define WT_BYTES    ((size_t)NCOLS * C_DIM * 2)
#define OFF_WRT     (OFF_WLT + WT_BYTES)

__device__ __forceinline__ void gload16(void* lds, const void* g) {
    __builtin_amdgcn_global_load_lds(
        (const __attribute__((address_space(1))) uint32_t*)g,
        (__attribute__((address_space(3))) uint32_t*)lds,
        16, 0, 0);
}

// ---- fused prep: blocks 0..127 W->WT bf16; 128..1279: x -> nodes + out block 4 ----
__global__ __launch_bounds__(256)
void prep_kernel(const float* __restrict__ x,
                 const float* __restrict__ Wl, const float* __restrict__ Wr,
                 bf16* __restrict__ nodes, bf16* __restrict__ WlT, bf16* __restrict__ WrT,
                 float* __restrict__ out)
{
    __shared__ char smem[33792];
    const int t = threadIdx.x;
    const int bid = blockIdx.x;
    if (bid < 128) {
        float (*tile)[65] = (float(*)[65])smem;
        const int sel = bid & 1;
        const int l = (bid >> 1) & 3;
        const int kt = ((bid >> 3) & 3) * 64;
        const int ct = ((bid >> 5) & 3) * 64;
        const float* W = sel ? Wr : Wl;
        bf16* WT = sel ? WrT : WlT;
        const int tc = t & 63;
        const int tk = t >> 6;
#pragma unroll
        for (int i = 0; i < 16; ++i) {
            int kl = i * 4 + tk;
            tile[kl][tc] = W[((size_t)(l * 256 + kt + kl)) * 256 + ct + tc];
        }
        __syncthreads();
#pragma unroll
        for (int i = 0; i < 16; ++i) {
            int cl = i * 4 + tk;
            WT[((size_t)(l * 256 + ct + cl)) * 256 + kt + tc] = __float2bfloat16(tile[tc][cl]);
        }
    } else {
        bf16 (*tile)[66] = (bf16(*)[66])smem;
        const int bid2 = bid - 128;
        const int b = bid2 / 18;
        const int n0 = (bid2 % 18) * 64;
        const int nl = t & 63;
        const int cs = t >> 6;
        const int n = n0 + nl;
        const bool nvalid = n < N_NODES;
        const float* xb = x + (size_t)b * CN;
        float* outb = out + (size_t)b * OUT_STRIDE_B + (size_t)4 * CN;
#pragma unroll 4
        for (int cc = 0; cc < 64; ++cc) {
            int c = cc * 4 + cs;
            if (nvalid) {
                float v = xb[(size_t)c * N_NODES + n];
                outb[(size_t)c * N_NODES + n] = v;
                tile[c][nl] = __float2bfloat16(v);
            }
        }
        __syncthreads();
        const int half = t >> 7;
        const int c0 = (t & 127) * 2;
#pragma unroll
        for (int it = 0; it < 32; ++it) {
            int row = it * 2 + half;
            int nr = n0 + row;
            if (nr < N_NODES) {
                __hip_bfloat162 p;
                p.x = tile[c0][row];
                p.y = tile[c0 + 1][row];
                *(__hip_bfloat162*)(nodes + ((size_t)b * N_NODES + nr) * C_DIM + c0) = p;
            }
        }
    }
}

// ---- analytic mean-aggregate; rows N_NODES..1151 zeroed ----
__global__ __launch_bounds__(256)
void gather_kernel(const bf16* __restrict__ nodes, bf16* __restrict__ aggb)
{
    const int n = blockIdx.x;        // 0..1151
    const int c = threadIdx.x;
    if (n >= N_NODES) {
        aggb[(size_t)n * C_DIM + c] = __float2bfloat16(0.f);
        return;
    }
    const int i = n / GRID_G, j = n % GRID_G;
    float s = 0.f, d = 0.f;
    if (j >= 2)           { s += __bfloat162float(nodes[(size_t)(n - 2)  * C_DIM + c]); d += 1.f; }
    if (i >= 2)           { s += __bfloat162float(nodes[(size_t)(n - 66) * C_DIM + c]); d += 1.f; }
    if (i >= 2 && j >= 2) { s += __bfloat162float(nodes[(size_t)(n - 68) * C_DIM + c]); d += 1.f; }
    if (i >= 2 && j >= 1 && j <= 30)
                          { s += __bfloat162float(nodes[(size_t)(n - 64) * C_DIM + c]); d += 1.f; }
    aggb[(size_t)n * C_DIM + c] = __float2bfloat16(d > 0.f ? s / d : 0.f);
}

// ---- persistent multi-job GEMM ----
__global__ __launch_bounds__(256)
void gemm_kernel(const bf16* __restrict__ nodes, const bf16* __restrict__ agg,
                 const bf16* __restrict__ WrT, const bf16* __restrict__ WlT,
                 const float* __restrict__ bias, float* __restrict__ out)
{
    __shared__ bf16 Alds[3][128 * 32];
    __shared__ bf16 Blds[3][128 * 32];
    const int t = threadIdx.x;
    const int lane = t & 63;
    const int w = t >> 6;
    // bid&7 = XCD (round-robin dispatch). 8 bcol-partners of a slot share an XCD.
    const unsigned bid = blockIdx.x;           // 768
    const int j6 = (int)(bid >> 3);            // 0..95
    const int bcol = j6 / 12;
    const int s = (int)(bid & 7) * 12 + (j6 - bcol * 12);   // slot 0..95
    const int T = (s < 65) ? 6 : 5;            // brows: s + 96g, g in [0,T)
    const bool mix = (s < 9);                  // brow s also needs agg@WlT pass
    const int nj = T + (mix ? 1 : 0);
    const int totalf = nj * 8;

    f32x4 acc[4][4] = {};

    const int tq = t >> 2;
    const int kk = (((t & 3) ^ ((tq >> 1) & 3)) << 3);   // inverse-swizzled source slot
    const int wr = (w >> 1) << 6;
    const int wc = (w & 1) << 6;
    const int fr = lane & 15;
    const int kq = lane >> 4;
    const int swzr = (kq ^ ((fr >> 1) & 3)) << 3;        // phys slot for reads (shorts)

    char* AldsB = (char*)Alds;
    char* BldsB = (char*)Blds;
    const short* AldsS = (const short*)Alds;
    const short* BldsS = (const short*)Blds;

    // job j: g = mix ? max(0,j-1) : j ; src = (mix && j==1) ? (agg,WlT) : (nodes,WrT)
    auto jobBrow = [&](int j) { int jg = mix ? (j <= 1 ? 0 : j - 1) : j; return s + 96 * jg; };
    auto jobA = [&](int j) -> const bf16* {
        const bf16* sa = (mix && j == 1) ? agg : nodes;
        return sa + ((size_t)jobBrow(j) * 128 + tq) * C_DIM + kk;
    };
    auto jobB = [&](int j) -> const bf16* {
        const bf16* sb = (mix && j == 1) ? WlT : WrT;
        return sb + ((size_t)bcol * 128 + tq) * C_DIM + kk;
    };

    auto stage4 = [&](const bf16* Ag, const bf16* Bg, int buf) {
        gload16(AldsB + buf * 8192 + w * 1024,        Ag);
        gload16(AldsB + buf * 8192 + 4096 + w * 1024, Ag + 64 * C_DIM);
        gload16(BldsB + buf * 8192 + w * 1024,        Bg);
        gload16(BldsB + buf * 8192 + 4096 + w * 1024, Bg + 64 * C_DIM);
    };

    auto EPILOGUE = [&](int brw) {
        const int rq = kq * 4;
        const int r0 = brw * 128 + wr + rq;
        const unsigned bb0 = (unsigned)r0 / N_NODES;
        const int rsw = (int)((bb0 + 1) * N_NODES);
        const int colbase = bcol * 128 + wc + fr;
        size_t coff[4];
        float bi[4];
#pragma unroll
        for (int n = 0; n < 4; ++n) {
            int col = colbase + n * 16;
            coff[n] = (size_t)(col >> 8) * CN + (col & 255);
            bi[n] = bias[col];
        }
#pragma unroll
        for (int m = 0; m < 4; ++m) {
#pragma unroll
            for (int reg = 0; reg < 4; ++reg) {
                int r = r0 + m * 16 + reg;
                if (r < TOTAL) {
                    int bb = (int)bb0 + (r >= rsw ? 1 : 0);
                    int nn = r - bb * N_NODES;
                    size_t base = (size_t)bb * OUT_STRIDE_B + (size_t)nn * C_DIM;
#pragma unroll
                    for (int n = 0; n < 4; ++n) {
                        float v = acc[m][n][reg] + bi[n];
                        v = v > 0.f ? v : (__expf(v) - 1.0f);
                        out[base + coff[n]] = v;
                    }
                }
            }
        }
    };

    // prologue: stage f=0,1 (job 0, k-slices 0,1)
    {
        const bf16* A0 = jobA(0);
        const bf16* B0 = jobB(0);
        stage4(A0,      B0,      0);
        stage4(A0 + 32, B0 + 32, 1);
    }
    int rb = 0;
    bool prevEpi = false;
    for (int j = 0; j < nj; ++j) {
        const bf16* curA = jobA(j);
        const bf16* curB = jobB(j);
        const int fbase = j * 8;
#pragma unroll
        for (int ss = 0; ss < 8; ++ss) {
            const int f = fbase + ss;
            // stores from a preceding epilogue share vmcnt (in-order) -> full drain once
            if (ss == 0 && prevEpi)     asm volatile("s_waitcnt vmcnt(0)" ::: "memory");
            else if (f + 1 < totalf)    asm volatile("s_waitcnt vmcnt(4)" ::: "memory");
            else                        asm volatile("s_waitcnt vmcnt(0)" ::: "memory");
            __builtin_amdgcn_s_barrier();
            if (f + 2 < totalf) {
                const int wb = rb == 0 ? 2 : (rb == 1 ? 0 : 1);
                if (ss < 6)       stage4(curA + (ss + 2) * 32, curB + (ss + 2) * 32, wb);
                else if (ss == 6) stage4(jobA(j + 1),      jobB(j + 1),      wb);
                else              stage4(jobA(j + 1) + 32, jobB(j + 1) + 32, wb);
            }
            const short* Ab = AldsS + rb * 4096;
            const short* Bb = BldsS + rb * 4096;
            short8 av[4], bv[4];
#pragma unroll
            for (int m = 0; m < 4; ++m)
                av[m] = *(const short8*)(Ab + (wr + m * 16 + fr) * 32 + swzr);
#pragma unroll
            for (int n = 0; n < 4; ++n)
                bv[n] = *(const short8*)(Bb + (wc + n * 16 + fr) * 32 + swzr);
#pragma unroll
            for (int m = 0; m < 4; ++m)
#pragma unroll
                for (int n = 0; n < 4; ++n)
                    acc[m][n] = __builtin_amdgcn_mfma_f32_16x16x32_bf16(
                        av[m], bv[n], acc[m][n], 0, 0, 0);
            rb = (rb == 2) ? 0 : rb + 1;
        }
        if (!(mix && j == 0)) {
            EPILOGUE(jobBrow(j));
#pragma unroll
            for (int m = 0; m < 4; ++m)
#pragma unroll
                for (int n = 0; n < 4; ++n)
                    acc[m][n] = (f32x4){0.f, 0.f, 0.f, 0.f};
            prevEpi = true;
        } else {
            prevEpi = false;   // mixed j=0: acc carries into the agg job
        }
    }
}

extern "C" void kernel_launch(void* const* d_in, const int* in_sizes, int n_in,
                              void* d_out, int out_size, void* d_ws, size_t ws_size,
                              hipStream_t stream) {
    const float* x  = (const float*)d_in[0];
    const float* Wl = (const float*)d_in[1];
    const float* bl = (const float*)d_in[2];
    const float* Wr = (const float*)d_in[3];
    float* out = (float*)d_out;
    char* ws = (char*)d_ws;

    bf16* nodes = (bf16*)(ws + OFF_NODES);
    bf16* aggb  = (bf16*)(ws + OFF_AGGB);
    bf16* WlT   = (bf16*)(ws + OFF_WLT);
    bf16* WrT   = (bf16*)(ws + OFF_WRT);

    prep_kernel<<<128 + BATCH * 18, 256, 0, stream>>>(x, Wl, Wr, nodes, WlT, WrT, out);
    gather_kernel<<<AGG_ROWS, 256, 0, stream>>>(nodes, aggb);
    gemm_kernel<<<768, 256, 0, stream>>>(nodes, aggb, WrT, WlT, bl, out);
}